// Round 21
// baseline (35.789 us; speedup 1.0000x reference)
//
#include <hip/hip_runtime.h>
#include <math.h>

#define B_  128
#define C_  3
#define L_  2048
#define K_  128
#define S_  50
#define W_  (L_ - S_ + 1)          /* 1999 */
#define XPAD 2112                  /* padded bf16 row length */
#define BIGW 1e30f

typedef __attribute__((ext_vector_type(8))) short bf16x8;
typedef __attribute__((ext_vector_type(4))) float f32x4;
typedef uint4 uint4_a4 __attribute__((aligned(4)));

__device__ __forceinline__ unsigned short f2bf(float f) {
    unsigned int u = __float_as_uint(f);
    u += 0x7FFFu + ((u >> 16) & 1u);   // RNE (inputs finite)
    return (unsigned short)(u >> 16);
}
__device__ __forceinline__ float bf2f(unsigned short h) {
    return __uint_as_float(((unsigned int)h) << 16);
}
__device__ __forceinline__ unsigned pack2(float a, float b) {
    return (unsigned)f2bf(a) | ((unsigned)f2bf(b) << 16);
}
__device__ __forceinline__ unsigned packsw(float s) {   // hi/lo compensated bf16 pair
    unsigned short hi = f2bf(s);
    unsigned short lo = f2bf(s - bf2f(hi));
    return (unsigned)hi | ((unsigned)lo << 16);
}

// ws layout (bytes):
//   sqwz: u32 [B_*C_*L_]  packed hi/lo bf16(||w||^2)  @ 0         (3,145,728)
//   xb0 : bf16[B_*C_*XPAD]                            @ 3145728   (1,622,016)
//   xb1 : bf16[B_*C_*XPAD] (shift 1)                  @ 4767744   (1,622,016)
//   frag: uint4[C_*2*8*64]                            @ 6389760   (49,152)
#define WS_SQWZ_OFF 0
#define WS_XB0_OFF  3145728
#define WS_XB1_OFF  4767744
#define WS_FRAG_OFF 6389760

// Fused prep, one x read total:
//   [0,384):   one block per (b,c) row: stage row in LDS -> bf16 parity pair
//              + rolling ||w||^2 pack (x read ONCE)
//   [384,396): B-fragments
//   [396,460): out init
__global__ __launch_bounds__(256) void prep_all(const float* __restrict__ x,
                                                const float* __restrict__ sh,
                                                unsigned* __restrict__ sqwz,
                                                unsigned* __restrict__ xb0,
                                                unsigned* __restrict__ xb1,
                                                uint4* __restrict__ ws_frag,
                                                float* __restrict__ out) {
    const int blk = blockIdx.x;
    if (blk < 384) {
        const int row = blk;
        const int t   = threadIdx.x;
        __shared__ float rowf[L_];           // 8 KB
        // stage: 8 f32 per thread
        {
            const float4* xr4 = (const float4*)(x + row * L_);
            float4 a = xr4[2 * t];
            float4 b = xr4[2 * t + 1];
            float4* rf4 = (float4*)rowf;
            rf4[2 * t]     = a;
            rf4[2 * t + 1] = b;
        }
        __syncthreads();
        // cvt: elems [8t, 8t+8) -> 4 words each parity
        {
            float e[9];
            #pragma unroll
            for (int j = 0; j < 8; ++j) e[j] = rowf[8 * t + j];
            e[8] = (t == 255) ? 0.f : rowf[8 * t + 8];
            uint4 q0, q1;
            q0.x = pack2(e[0], e[1]); q0.y = pack2(e[2], e[3]);
            q0.z = pack2(e[4], e[5]); q0.w = pack2(e[6], e[7]);
            q1.x = pack2(e[1], e[2]); q1.y = pack2(e[3], e[4]);
            q1.z = pack2(e[5], e[6]); q1.w = pack2(e[7], e[8]);
            *(uint4*)(xb0 + row * (XPAD / 2) + 4 * t) = q0;
            *(uint4*)(xb1 + row * (XPAD / 2) + 4 * t) = q1;
            if (t < 8) {   // tail pad words [1024,1056): elems 2048..2111 = 0
                uint4 zz = {0u, 0u, 0u, 0u};
                *(uint4*)(xb0 + row * (XPAD / 2) + 1024 + 4 * t) = zz;
                *(uint4*)(xb1 + row * (XPAD / 2) + 1024 + 4 * t) = zz;
            }
        }
        // sqw: windows [8t, 8t+8), rolling from LDS
        {
            unsigned* op = sqwz + row * L_ + 8 * t;
            const int wb = 8 * t;
            if (wb + 7 < W_) {               // t <= 248: all 8 valid, reads <= wb+56
                float e[57];
                #pragma unroll
                for (int j = 0; j < 57; ++j) e[j] = rowf[wb + j];
                float s = 0.f;
                #pragma unroll
                for (int j = 0; j < S_; ++j) s += e[j] * e[j];
                op[0] = packsw(s);
                #pragma unroll
                for (int w = 1; w < 8; ++w) {
                    s += e[w + 49] * e[w + 49] - e[w - 1] * e[w - 1];
                    op[w] = packsw(s);
                }
            } else {
                for (int i = 0; i < 8; ++i) {
                    int w = wb + i;
                    float r = BIGW;
                    if (w < W_) {
                        r = 0.f;
                        #pragma unroll 10
                        for (int j = 0; j < S_; ++j) { float v = rowf[w + j]; r += v * v; }
                    }
                    op[i] = packsw(r);
                }
            }
        }
    } else if (blk < 396) {
        // B-fragments, -2x scaled; K-pad rows 50/51 = ss hi/lo, 52/53 = 1.0
        int t  = (blk - 384) * 256 + threadIdx.x;    // 0..3071
        int c  = t >> 10;
        int rem = t & 1023;
        int ks = rem >> 9;
        int nq = (rem >> 6) & 7;
        int l  = rem & 63;
        int k  = nq * 16 + (l & 15);
        int s0 = ks * 32 + (l >> 4) * 8;
        const float* sp = sh + (c * K_ + k) * S_;
        float ss = 0.f;
        #pragma unroll 10
        for (int s = 0; s < S_; ++s) { float v = sp[s]; ss += v * v; }
        unsigned short ss_hi = f2bf(ss);
        unsigned short ss_lo = f2bf(ss - bf2f(ss_hi));
        unsigned short h[8];
        #pragma unroll
        for (int j = 0; j < 8; ++j) {
            int s = s0 + j;
            unsigned short v;
            if      (s < S_)             v = f2bf(-2.f * sp[s]);
            else if (s == 50)            v = ss_hi;
            else if (s == 51)            v = ss_lo;
            else if (s == 52 || s == 53) v = 0x3F80;   // 1.0 bf16
            else                         v = 0;
            h[j] = v;
        }
        uint4 u;
        u.x = (unsigned)h[0] | ((unsigned)h[1] << 16);
        u.y = (unsigned)h[2] | ((unsigned)h[3] << 16);
        u.z = (unsigned)h[4] | ((unsigned)h[5] << 16);
        u.w = (unsigned)h[6] | ((unsigned)h[7] << 16);
        ws_frag[t] = u;
    } else {
        int i = (blk - 396) * 256 + threadIdx.x;     // 0..16383
        out[i] = __int_as_float(0x7F800000);         // +inf
    }
}

// Block = (b, 256-window tile), 512 thr = 8 waves x 32 windows, full K=128.
// (512,6): VGPR cap 85 -> 6 waves/SIMD. This round: independent ks0/ks1 MFMA
// accumulators (breaks the 2-MFMA serial chain; both issue back-to-back) with
// the join done as f32x4 vector adds -> v_pk_add_f32 (net-zero VALU issue:
// +2 pk_add replaces the chain, dsum accumulate also vectorized to pk_add).
__global__ __launch_bounds__(512, 6) void mfma_main(
        const unsigned* __restrict__ sqwz,
        const char* __restrict__ xb0,
        const char* __restrict__ xb1,
        const uint4* __restrict__ ws_frag,
        float* __restrict__ out) {
    // XCD swizzle: grid 1024 = 8 XCDs x 128 contiguous units
    const int u    = (blockIdx.x & 7) * 128 + (blockIdx.x >> 3);
    const int b    = u >> 3;
    const int tile = u & 7;
    const int w0   = tile * 256;
    const int t    = threadIdx.x;
    const int wid  = t >> 6;                 // 0..7
    const int l    = t & 63;
    const int row  = l & 15;
    const int kg   = l >> 4;
    const int wbase = w0 + wid * 32 + row;   // A-tile0 window; tile1 = +16
    const int eb0   = wbase + kg * 8;

    __shared__ uint4 sF[3072];               // 48 KB: full B-fragment array
    __shared__ float bmin[8][K_];            // 4 KB

    // stage B-fragments: 6 rounds of direct global->LDS DMA (no VGPR roundtrip).
    #pragma unroll
    for (int j = 0; j < 6; ++j) {
        const unsigned* gp = (const unsigned*)(ws_frag + t + j * 512);
        __builtin_amdgcn_global_load_lds(
            (const __attribute__((address_space(1))) unsigned*)gp,
            (__attribute__((address_space(3))) unsigned*)&sF[t + j * 512],
            16, 0, 0);
    }

    // parity-aligned bf16 base (4B-aligned for both parities); tile1 +32B, ks1 +64B
    const char* xbase = (wbase & 1) ? (xb1 + 2 * (eb0 - 1)) : (xb0 + 2 * eb0);
    const unsigned* szp = sqwz + b * C_ * L_ + wbase;

    // A-fragments: 3 channels x {tile0,tile1} x {ks0,ks1} = 12 uint4 (registers)
    uint4 A00[3], A10[3], A01[3], A11[3];
    #pragma unroll
    for (int c = 0; c < C_; ++c) {
        const char* xp = xbase + (b * C_ + c) * (XPAD * 2);
        A00[c] = *(const uint4_a4*)(xp);
        A10[c] = *(const uint4_a4*)(xp + 64);
        A01[c] = *(const uint4_a4*)(xp + 32);
        A11[c] = *(const uint4_a4*)(xp + 96);
        unsigned wz0 = szp[c * L_];
        unsigned wz1 = szp[c * L_ + 16];
        if (kg == 2) {   // ks1 s=50,51 -> 1.0 (x ss rows); s=52,53 -> sw hi/lo (x 1.0 rows)
            A10[c].y = 0x3F803F80u; A10[c].z = wz0;
            A11[c].y = 0x3F803F80u; A11[c].z = wz1;
        }
    }
    __syncthreads();   // drains vmcnt -> sF valid

    #pragma unroll
    for (int i = 0; i < 8; ++i) {
        const int nq = (i + wid) & 7;        // de-phased: waves start staggered
        f32x4 ds0 = (f32x4){0.f, 0.f, 0.f, 0.f};
        f32x4 ds1 = (f32x4){0.f, 0.f, 0.f, 0.f};
        #pragma unroll
        for (int c = 0; c < C_; ++c) {
            uint4 b0 = sF[c * 1024 +       nq * 64 + l];   // ds_read_b128
            uint4 b1 = sF[c * 1024 + 512 + nq * 64 + l];
            f32x4 z = (f32x4){0.f, 0.f, 0.f, 0.f};
            f32x4 a0a, a0b, a1a, a1b;
            __builtin_amdgcn_s_setprio(1);
            // 4 INDEPENDENT MFMAs (no serial acc chain)
            a0a = __builtin_amdgcn_mfma_f32_16x16x32_bf16(
                      __builtin_bit_cast(bf16x8, A00[c]), __builtin_bit_cast(bf16x8, b0), z, 0, 0, 0);
            a1a = __builtin_amdgcn_mfma_f32_16x16x32_bf16(
                      __builtin_bit_cast(bf16x8, A01[c]), __builtin_bit_cast(bf16x8, b0), z, 0, 0, 0);
            a0b = __builtin_amdgcn_mfma_f32_16x16x32_bf16(
                      __builtin_bit_cast(bf16x8, A10[c]), __builtin_bit_cast(bf16x8, b1), z, 0, 0, 0);
            a1b = __builtin_amdgcn_mfma_f32_16x16x32_bf16(
                      __builtin_bit_cast(bf16x8, A11[c]), __builtin_bit_cast(bf16x8, b1), z, 0, 0, 0);
            __builtin_amdgcn_s_setprio(0);
            // d^2 = ks0 part + ks1 part  (f32x4 add -> v_pk_add_f32 pairs)
            f32x4 d20 = a0a + a0b;
            f32x4 d21 = a1a + a1b;
            f32x4 s0, s1;
            #pragma unroll
            for (int r = 0; r < 4; ++r) {
                s0[r] = __builtin_amdgcn_sqrtf(__builtin_fabsf(d20[r]));
                s1[r] = __builtin_amdgcn_sqrtf(__builtin_fabsf(d21[r]));
            }
            ds0 += s0;   // vector accumulate -> pk_add
            ds1 += s1;
        }
        float m = fminf(fminf(ds0[0], ds0[1]), fminf(ds0[2], ds0[3]));
        float n = fminf(fminf(ds1[0], ds1[1]), fminf(ds1[2], ds1[3]));
        m = fminf(m, n);
        m = fminf(m, __shfl_xor(m, 16));
        m = fminf(m, __shfl_xor(m, 32));
        if (kg == 0) bmin[wid][nq * 16 + row] = m;
    }
    __syncthreads();
    if (t < K_) {
        float v = bmin[0][t];
        #pragma unroll
        for (int q = 1; q < 8; ++q) v = fminf(v, bmin[q][t]);
        atomicMin(reinterpret_cast<int*>(out) + b * K_ + t, __float_as_int(v));
    }
}

extern "C" void kernel_launch(void* const* d_in, const int* in_sizes, int n_in,
                              void* d_out, int out_size, void* d_ws, size_t ws_size,
                              hipStream_t stream) {
    const float* x  = (const float*)d_in[0];   // (128,3,2048) f32
    const float* sh = (const float*)d_in[1];   // (3,128,50)  f32
    float* out = (float*)d_out;                // (128,1,128) f32

    unsigned* ws_sqwz = (unsigned*)((char*)d_ws + WS_SQWZ_OFF);
    unsigned* ws_xb0  = (unsigned*)((char*)d_ws + WS_XB0_OFF);
    unsigned* ws_xb1  = (unsigned*)((char*)d_ws + WS_XB1_OFF);
    uint4*    ws_frag = (uint4*)((char*)d_ws + WS_FRAG_OFF);

    prep_all<<<460, 256, 0, stream>>>(x, sh, ws_sqwz, ws_xb0, ws_xb1, ws_frag, out);
    mfma_main<<<128 * 8, 512, 0, stream>>>(
        ws_sqwz, (const char*)ws_xb0, (const char*)ws_xb1, ws_frag, out);
}

// Round 22
// 31.432 us; speedup vs baseline: 1.1386x; 1.1386x over previous
//
#include <hip/hip_runtime.h>
#include <math.h>

#define B_  128
#define C_  3
#define L_  2048
#define K_  128
#define S_  50
#define W_  (L_ - S_ + 1)          /* 1999 */
#define XPAD 2112                  /* padded bf16 row length */
#define BIGW 1e30f

typedef __attribute__((ext_vector_type(8))) short bf16x8;
typedef __attribute__((ext_vector_type(4))) float f32x4;
typedef uint4 uint4_a4 __attribute__((aligned(4)));

__device__ __forceinline__ unsigned short f2bf(float f) {
    unsigned int u = __float_as_uint(f);
    u += 0x7FFFu + ((u >> 16) & 1u);   // RNE (inputs finite)
    return (unsigned short)(u >> 16);
}
__device__ __forceinline__ float bf2f(unsigned short h) {
    return __uint_as_float(((unsigned int)h) << 16);
}
__device__ __forceinline__ unsigned pack2(float a, float b) {
    return (unsigned)f2bf(a) | ((unsigned)f2bf(b) << 16);
}
__device__ __forceinline__ unsigned packsw(float s) {   // hi/lo compensated bf16 pair
    unsigned short hi = f2bf(s);
    unsigned short lo = f2bf(s - bf2f(hi));
    return (unsigned)hi | ((unsigned)lo << 16);
}

// ws layout (bytes):
//   sqwz: u32 [B_*C_*L_]  packed hi/lo bf16(||w||^2)  @ 0         (3,145,728)
//   xb0 : bf16[B_*C_*XPAD]                            @ 3145728   (1,622,016)
//   xb1 : bf16[B_*C_*XPAD] (shift 1)                  @ 4767744   (1,622,016)
//   frag: uint4[C_*2*8*64]                            @ 6389760   (49,152)
#define WS_SQWZ_OFF 0
#define WS_XB0_OFF  3145728
#define WS_XB1_OFF  4767744
#define WS_FRAG_OFF 6389760

// Fused prep, one x read total:
//   [0,384):   one block per (b,c) row: stage row in LDS -> bf16 parity pair
//              + rolling ||w||^2 pack (x read ONCE)
//   [384,396): B-fragments
//   [396,460): out init
__global__ __launch_bounds__(256) void prep_all(const float* __restrict__ x,
                                                const float* __restrict__ sh,
                                                unsigned* __restrict__ sqwz,
                                                unsigned* __restrict__ xb0,
                                                unsigned* __restrict__ xb1,
                                                uint4* __restrict__ ws_frag,
                                                float* __restrict__ out) {
    const int blk = blockIdx.x;
    if (blk < 384) {
        const int row = blk;
        const int t   = threadIdx.x;
        __shared__ float rowf[L_];           // 8 KB
        // stage: 8 f32 per thread
        {
            const float4* xr4 = (const float4*)(x + row * L_);
            float4 a = xr4[2 * t];
            float4 b = xr4[2 * t + 1];
            float4* rf4 = (float4*)rowf;
            rf4[2 * t]     = a;
            rf4[2 * t + 1] = b;
        }
        __syncthreads();
        // cvt: elems [8t, 8t+8) -> 4 words each parity
        {
            float e[9];
            #pragma unroll
            for (int j = 0; j < 8; ++j) e[j] = rowf[8 * t + j];
            e[8] = (t == 255) ? 0.f : rowf[8 * t + 8];
            uint4 q0, q1;
            q0.x = pack2(e[0], e[1]); q0.y = pack2(e[2], e[3]);
            q0.z = pack2(e[4], e[5]); q0.w = pack2(e[6], e[7]);
            q1.x = pack2(e[1], e[2]); q1.y = pack2(e[3], e[4]);
            q1.z = pack2(e[5], e[6]); q1.w = pack2(e[7], e[8]);
            *(uint4*)(xb0 + row * (XPAD / 2) + 4 * t) = q0;
            *(uint4*)(xb1 + row * (XPAD / 2) + 4 * t) = q1;
            if (t < 8) {   // tail pad words [1024,1056): elems 2048..2111 = 0
                uint4 zz = {0u, 0u, 0u, 0u};
                *(uint4*)(xb0 + row * (XPAD / 2) + 1024 + 4 * t) = zz;
                *(uint4*)(xb1 + row * (XPAD / 2) + 1024 + 4 * t) = zz;
            }
        }
        // sqw: windows [8t, 8t+8), rolling from LDS
        {
            unsigned* op = sqwz + row * L_ + 8 * t;
            const int wb = 8 * t;
            if (wb + 7 < W_) {               // t <= 248: all 8 valid, reads <= wb+56
                float e[57];
                #pragma unroll
                for (int j = 0; j < 57; ++j) e[j] = rowf[wb + j];
                float s = 0.f;
                #pragma unroll
                for (int j = 0; j < S_; ++j) s += e[j] * e[j];
                op[0] = packsw(s);
                #pragma unroll
                for (int w = 1; w < 8; ++w) {
                    s += e[w + 49] * e[w + 49] - e[w - 1] * e[w - 1];
                    op[w] = packsw(s);
                }
            } else {
                for (int i = 0; i < 8; ++i) {
                    int w = wb + i;
                    float r = BIGW;
                    if (w < W_) {
                        r = 0.f;
                        #pragma unroll 10
                        for (int j = 0; j < S_; ++j) { float v = rowf[w + j]; r += v * v; }
                    }
                    op[i] = packsw(r);
                }
            }
        }
    } else if (blk < 396) {
        // B-fragments, -2x scaled; K-pad rows 50/51 = ss hi/lo, 52/53 = 1.0
        int t  = (blk - 384) * 256 + threadIdx.x;    // 0..3071
        int c  = t >> 10;
        int rem = t & 1023;
        int ks = rem >> 9;
        int nq = (rem >> 6) & 7;
        int l  = rem & 63;
        int k  = nq * 16 + (l & 15);
        int s0 = ks * 32 + (l >> 4) * 8;
        const float* sp = sh + (c * K_ + k) * S_;
        float ss = 0.f;
        #pragma unroll 10
        for (int s = 0; s < S_; ++s) { float v = sp[s]; ss += v * v; }
        unsigned short ss_hi = f2bf(ss);
        unsigned short ss_lo = f2bf(ss - bf2f(ss_hi));
        unsigned short h[8];
        #pragma unroll
        for (int j = 0; j < 8; ++j) {
            int s = s0 + j;
            unsigned short v;
            if      (s < S_)             v = f2bf(-2.f * sp[s]);
            else if (s == 50)            v = ss_hi;
            else if (s == 51)            v = ss_lo;
            else if (s == 52 || s == 53) v = 0x3F80;   // 1.0 bf16
            else                         v = 0;
            h[j] = v;
        }
        uint4 u;
        u.x = (unsigned)h[0] | ((unsigned)h[1] << 16);
        u.y = (unsigned)h[2] | ((unsigned)h[3] << 16);
        u.z = (unsigned)h[4] | ((unsigned)h[5] << 16);
        u.w = (unsigned)h[6] | ((unsigned)h[7] << 16);
        ws_frag[t] = u;
    } else {
        int i = (blk - 396) * 256 + threadIdx.x;     // 0..16383
        out[i] = __int_as_float(0x7F800000);         // +inf
    }
}

// Block = (b, 256-window tile), 512 thr = 8 waves x 32 windows, full K=128.
// (512,6): VGPR cap 85 -> 6 waves/SIMD. Serial 2-MFMA acc chain is kept
// deliberately: it holds only 2 live accumulators (R21's 4-independent-acc
// variant tipped the cap and regressed 31.4->35.8us). De-phased nq start +
// XCD swizzle + global_load_lds DMA + setprio around MFMA (R19/R20 wins).
__global__ __launch_bounds__(512, 6) void mfma_main(
        const unsigned* __restrict__ sqwz,
        const char* __restrict__ xb0,
        const char* __restrict__ xb1,
        const uint4* __restrict__ ws_frag,
        float* __restrict__ out) {
    // XCD swizzle: grid 1024 = 8 XCDs x 128 contiguous units
    const int u    = (blockIdx.x & 7) * 128 + (blockIdx.x >> 3);
    const int b    = u >> 3;
    const int tile = u & 7;
    const int w0   = tile * 256;
    const int t    = threadIdx.x;
    const int wid  = t >> 6;                 // 0..7
    const int l    = t & 63;
    const int row  = l & 15;
    const int kg   = l >> 4;
    const int wbase = w0 + wid * 32 + row;   // A-tile0 window; tile1 = +16
    const int eb0   = wbase + kg * 8;

    __shared__ uint4 sF[3072];               // 48 KB: full B-fragment array
    __shared__ float bmin[8][K_];            // 4 KB

    // stage B-fragments: 6 rounds of direct global->LDS DMA (no VGPR roundtrip).
    #pragma unroll
    for (int j = 0; j < 6; ++j) {
        const unsigned* gp = (const unsigned*)(ws_frag + t + j * 512);
        __builtin_amdgcn_global_load_lds(
            (const __attribute__((address_space(1))) unsigned*)gp,
            (__attribute__((address_space(3))) unsigned*)&sF[t + j * 512],
            16, 0, 0);
    }

    // parity-aligned bf16 base (4B-aligned for both parities); tile1 +32B, ks1 +64B
    const char* xbase = (wbase & 1) ? (xb1 + 2 * (eb0 - 1)) : (xb0 + 2 * eb0);
    const unsigned* szp = sqwz + b * C_ * L_ + wbase;

    // A-fragments: 3 channels x {tile0,tile1} x {ks0,ks1} = 12 uint4 (registers)
    uint4 A00[3], A10[3], A01[3], A11[3];
    #pragma unroll
    for (int c = 0; c < C_; ++c) {
        const char* xp = xbase + (b * C_ + c) * (XPAD * 2);
        A00[c] = *(const uint4_a4*)(xp);
        A10[c] = *(const uint4_a4*)(xp + 64);
        A01[c] = *(const uint4_a4*)(xp + 32);
        A11[c] = *(const uint4_a4*)(xp + 96);
        unsigned wz0 = szp[c * L_];
        unsigned wz1 = szp[c * L_ + 16];
        if (kg == 2) {   // ks1 s=50,51 -> 1.0 (x ss rows); s=52,53 -> sw hi/lo (x 1.0 rows)
            A10[c].y = 0x3F803F80u; A10[c].z = wz0;
            A11[c].y = 0x3F803F80u; A11[c].z = wz1;
        }
    }
    __syncthreads();   // drains vmcnt -> sF valid

    #pragma unroll
    for (int i = 0; i < 8; ++i) {
        const int nq = (i + wid) & 7;        // de-phased: waves start staggered
        f32x4 ds0 = (f32x4){0.f, 0.f, 0.f, 0.f};
        f32x4 ds1 = (f32x4){0.f, 0.f, 0.f, 0.f};
        #pragma unroll
        for (int c = 0; c < C_; ++c) {
            uint4 b0 = sF[c * 1024 +       nq * 64 + l];   // ds_read_b128
            uint4 b1 = sF[c * 1024 + 512 + nq * 64 + l];
            f32x4 z = (f32x4){0.f, 0.f, 0.f, 0.f};
            f32x4 acc0, acc1;
            __builtin_amdgcn_s_setprio(1);
            acc0 = __builtin_amdgcn_mfma_f32_16x16x32_bf16(
                       __builtin_bit_cast(bf16x8, A00[c]), __builtin_bit_cast(bf16x8, b0), z, 0, 0, 0);
            acc1 = __builtin_amdgcn_mfma_f32_16x16x32_bf16(
                       __builtin_bit_cast(bf16x8, A01[c]), __builtin_bit_cast(bf16x8, b0), z, 0, 0, 0);
            acc0 = __builtin_amdgcn_mfma_f32_16x16x32_bf16(
                       __builtin_bit_cast(bf16x8, A10[c]), __builtin_bit_cast(bf16x8, b1), acc0, 0, 0, 0);
            acc1 = __builtin_amdgcn_mfma_f32_16x16x32_bf16(
                       __builtin_bit_cast(bf16x8, A11[c]), __builtin_bit_cast(bf16x8, b1), acc1, 0, 0, 0);
            __builtin_amdgcn_s_setprio(0);
            // acc = ||w||^2 + ||s||^2 - 2*dot ; |abs| folds into v_sqrt operand
            #pragma unroll
            for (int r = 0; r < 4; ++r) {
                ds0[r] += __builtin_amdgcn_sqrtf(__builtin_fabsf(acc0[r]));
                ds1[r] += __builtin_amdgcn_sqrtf(__builtin_fabsf(acc1[r]));
            }
        }
        float m = fminf(fminf(ds0[0], ds0[1]), fminf(ds0[2], ds0[3]));
        float n = fminf(fminf(ds1[0], ds1[1]), fminf(ds1[2], ds1[3]));
        m = fminf(m, n);
        m = fminf(m, __shfl_xor(m, 16));
        m = fminf(m, __shfl_xor(m, 32));
        if (kg == 0) bmin[wid][nq * 16 + row] = m;
    }
    __syncthreads();
    if (t < K_) {
        float v = bmin[0][t];
        #pragma unroll
        for (int q = 1; q < 8; ++q) v = fminf(v, bmin[q][t]);
        atomicMin(reinterpret_cast<int*>(out) + b * K_ + t, __float_as_int(v));
    }
}

extern "C" void kernel_launch(void* const* d_in, const int* in_sizes, int n_in,
                              void* d_out, int out_size, void* d_ws, size_t ws_size,
                              hipStream_t stream) {
    const float* x  = (const float*)d_in[0];   // (128,3,2048) f32
    const float* sh = (const float*)d_in[1];   // (3,128,50)  f32
    float* out = (float*)d_out;                // (128,1,128) f32

    unsigned* ws_sqwz = (unsigned*)((char*)d_ws + WS_SQWZ_OFF);
    unsigned* ws_xb0  = (unsigned*)((char*)d_ws + WS_XB0_OFF);
    unsigned* ws_xb1  = (unsigned*)((char*)d_ws + WS_XB1_OFF);
    uint4*    ws_frag = (uint4*)((char*)d_ws + WS_FRAG_OFF);

    prep_all<<<460, 256, 0, stream>>>(x, sh, ws_sqwz, ws_xb0, ws_xb1, ws_frag, out);
    mfma_main<<<128 * 8, 512, 0, stream>>>(
        ws_sqwz, (const char*)ws_xb0, (const char*)ws_xb1, ws_frag, out);
}